// Round 10
// baseline (130.114 us; speedup 1.0000x reference)
//
#include <hip/hip_runtime.h>

typedef unsigned short u16;
typedef unsigned int u32;
typedef __attribute__((ext_vector_type(8))) short short8;   // bf16x8 MFMA frag
typedef __attribute__((ext_vector_type(4))) float f32x4;    // MFMA acc frag

// Problem constants (match reference)
constexpr int NODES = 100000;
constexpr int EDGES = 800000;
constexpr int DIM = 128;       // node dim
constexpr int EDIM = 8;        // edge attr dim
constexpr int HEADS = 8;

__device__ inline u16 f2bf(float f) {              // f32 -> bf16 RNE
    u32 u = __float_as_uint(f);
    u = (u + 0x7FFFu + ((u >> 16) & 1u)) >> 16;
    return (u16)u;
}
__device__ inline float bf2f(u16 s) {              // bf16 -> f32 exact
    return __uint_as_float(((u32)s) << 16);
}
__device__ inline u32 packbf(float a, float b) {
    return (u32)f2bf(a) | ((u32)f2bf(b) << 16);
}

// ---------------------------------------------------------------------------
// node_proj via MFMA (standalone; R4-proven structure, inline W f32->bf16
// staging). 34.8KB LDS -> 4 blocks/CU, fine for an MFMA+streaming kernel.
// ---------------------------------------------------------------------------
__global__ __launch_bounds__(256) void node_proj_mfma(const float* __restrict__ x,
                                                      const float* __restrict__ Wn,
                                                      const float* __restrict__ bn,
                                                      u16* __restrict__ xpb) {
    __shared__ u16 sW[128 * 136];   // 34816 B, +8 pad per row

    const int tid = threadIdx.x;
    {   // stage W: f32 global -> bf16 LDS, 128 rows x 16 chunks of 8
        #pragma unroll
        for (int i = tid; i < 128 * 16; i += 256) {
            int row = i >> 4, ch = i & 15;
            const float* p = Wn + row * DIM + ch * 8;
            float4 f0 = *reinterpret_cast<const float4*>(p);
            float4 f1 = *reinterpret_cast<const float4*>(p + 4);
            short8 v;
            v[0]=(short)f2bf(f0.x); v[1]=(short)f2bf(f0.y);
            v[2]=(short)f2bf(f0.z); v[3]=(short)f2bf(f0.w);
            v[4]=(short)f2bf(f1.x); v[5]=(short)f2bf(f1.y);
            v[6]=(short)f2bf(f1.z); v[7]=(short)f2bf(f1.w);
            *reinterpret_cast<short8*>(&sW[row * 136 + ch * 8]) = v;
        }
    }
    __syncthreads();

    const int w = tid >> 6;        // wave 0..3
    const int l = tid & 63;
    const int lr = l & 15;
    const int lh = l >> 4;
    const int m0 = blockIdx.x * 128 + w * 32;

    f32x4 acc[2][8];
    #pragma unroll
    for (int mt = 0; mt < 2; ++mt)
        #pragma unroll
        for (int nt = 0; nt < 8; ++nt) acc[mt][nt] = f32x4{0, 0, 0, 0};

    #pragma unroll
    for (int kk = 0; kk < 4; ++kk) {
        const int kb = kk * 32 + lh * 8;
        short8 a0, a1;
        {
            int row = m0 + lr;  row = row < NODES ? row : 0;
            const float* p = x + (size_t)row * DIM + kb;
            float4 f0 = *reinterpret_cast<const float4*>(p);
            float4 f1 = *reinterpret_cast<const float4*>(p + 4);
            a0[0]=(short)f2bf(f0.x); a0[1]=(short)f2bf(f0.y);
            a0[2]=(short)f2bf(f0.z); a0[3]=(short)f2bf(f0.w);
            a0[4]=(short)f2bf(f1.x); a0[5]=(short)f2bf(f1.y);
            a0[6]=(short)f2bf(f1.z); a0[7]=(short)f2bf(f1.w);
        }
        {
            int row = m0 + 16 + lr;  row = row < NODES ? row : 0;
            const float* p = x + (size_t)row * DIM + kb;
            float4 f0 = *reinterpret_cast<const float4*>(p);
            float4 f1 = *reinterpret_cast<const float4*>(p + 4);
            a1[0]=(short)f2bf(f0.x); a1[1]=(short)f2bf(f0.y);
            a1[2]=(short)f2bf(f0.z); a1[3]=(short)f2bf(f0.w);
            a1[4]=(short)f2bf(f1.x); a1[5]=(short)f2bf(f1.y);
            a1[6]=(short)f2bf(f1.z); a1[7]=(short)f2bf(f1.w);
        }
        #pragma unroll
        for (int nt = 0; nt < 8; ++nt) {
            short8 b = *reinterpret_cast<const short8*>(&sW[(nt * 16 + lr) * 136 + kb]);
            acc[0][nt] = __builtin_amdgcn_mfma_f32_16x16x32_bf16(a0, b, acc[0][nt], 0, 0, 0);
            acc[1][nt] = __builtin_amdgcn_mfma_f32_16x16x32_bf16(a1, b, acc[1][nt], 0, 0, 0);
        }
    }

    float bias[8];
    #pragma unroll
    for (int nt = 0; nt < 8; ++nt) bias[nt] = bn[nt * 16 + lr];

    #pragma unroll
    for (int mt = 0; mt < 2; ++mt) {
        #pragma unroll
        for (int r = 0; r < 4; ++r) {
            int grow = m0 + mt * 16 + lh * 4 + r;
            if (grow < NODES) {
                #pragma unroll
                for (int nt = 0; nt < 8; ++nt)
                    xpb[(size_t)grow * DIM + nt * 16 + lr] =
                        f2bf(acc[mt][nt][r] + bias[nt]);
            }
        }
    }
}

// ---------------------------------------------------------------------------
// build_rec (standalone, 288B LDS -> full occupancy): fused link-build + gate.
// Record (32B, coalesced at index e):
//   [0,4): next  [4,8): src  [8,24): 8 gates bf16  [24,32): pad
// 4-way split lists: head4[tgt*4 + (e&3)] -> 4 chains/node, mean len 2.
// ---------------------------------------------------------------------------
__global__ __launch_bounds__(256) void build_rec(const int* __restrict__ ei,
                                                 const float* __restrict__ ea,
                                                 const float* __restrict__ We,
                                                 const float* __restrict__ be,
                                                 int* __restrict__ head4,
                                                 uint4* __restrict__ rec) {
    __shared__ float sW[HEADS * EDIM];
    __shared__ float sb[HEADS];
    if (threadIdx.x < HEADS * EDIM) sW[threadIdx.x] = We[threadIdx.x];
    if (threadIdx.x < HEADS) sb[threadIdx.x] = be[threadIdx.x];
    __syncthreads();

    const int e = blockIdx.x * 256 + threadIdx.x;
    if (e >= EDGES) return;

    const int src = ei[e];
    const int tgt = ei[EDGES + e];
    float4 a0 = *reinterpret_cast<const float4*>(ea + (size_t)e * EDIM);
    float4 a1 = *reinterpret_cast<const float4*>(ea + (size_t)e * EDIM + 4);

    float g[HEADS];
    #pragma unroll
    for (int h = 0; h < HEADS; ++h) {
        const float* w = &sW[h * EDIM];
        float z = sb[h]
                + a0.x * w[0] + a0.y * w[1] + a0.z * w[2] + a0.w * w[3]
                + a1.x * w[4] + a1.y * w[5] + a1.z * w[6] + a1.w * w[7];
        g[h] = 1.0f / (1.0f + __expf(-z));
    }

    int nx = atomicExch(&head4[tgt * 4 + (e & 3)], e);

    uint4 r0, r1;
    r0.x = (u32)nx;
    r0.y = (u32)src;
    r0.z = packbf(g[0], g[1]);
    r0.w = packbf(g[2], g[3]);
    r1.x = packbf(g[4], g[5]);
    r1.y = packbf(g[6], g[7]);
    r1.z = 0; r1.w = 0;
    rec[(size_t)e * 2 + 0] = r0;      // coalesced 32B
    rec[(size_t)e * 2 + 1] = r1;
}

// ---------------------------------------------------------------------------
// aggregate_v8: 8-lane group per node (lane == head, owns 16 cols = 32B).
// 8 groups/wave x 4 chains = 32 independent chains in flight per wave.
// Branchless: clamped index + masked accumulate. Non-temporal out stores.
// ---------------------------------------------------------------------------
__global__ __launch_bounds__(256) void aggregate_v8(const u16* __restrict__ xpb,
                                                    const int* __restrict__ head4,
                                                    const char* __restrict__ recB,
                                                    float* __restrict__ out) {
    const int n = blockIdx.x * 32 + (threadIdx.x >> 3);
    if (n >= NODES) return;
    const int l = threadIdx.x & 7;     // lane in group == head index

    float acc[16];
    #pragma unroll
    for (int i = 0; i < 16; ++i) acc[i] = 0.0f;

    int e0 = head4[n * 4 + 0];
    int e1 = head4[n * 4 + 1];
    int e2 = head4[n * 4 + 2];
    int e3 = head4[n * 4 + 3];

    while (e0 >= 0 || e1 >= 0 || e2 >= 0 || e3 >= 0) {
        int c0 = e0 >= 0 ? e0 : 0;
        int c1 = e1 >= 0 ? e1 : 0;
        int c2 = e2 >= 0 ? e2 : 0;
        int c3 = e3 >= 0 ? e3 : 0;
        const char* r0 = recB + (size_t)c0 * 32;
        const char* r1 = recB + (size_t)c1 * 32;
        const char* r2 = recB + (size_t)c2 * 32;
        const char* r3 = recB + (size_t)c3 * 32;
        int2 ns0 = *reinterpret_cast<const int2*>(r0);
        int2 ns1 = *reinterpret_cast<const int2*>(r1);
        int2 ns2 = *reinterpret_cast<const int2*>(r2);
        int2 ns3 = *reinterpret_cast<const int2*>(r3);
        float g0 = bf2f(*reinterpret_cast<const u16*>(r0 + 8 + 2 * l));
        float g1 = bf2f(*reinterpret_cast<const u16*>(r1 + 8 + 2 * l));
        float g2 = bf2f(*reinterpret_cast<const u16*>(r2 + 8 + 2 * l));
        float g3 = bf2f(*reinterpret_cast<const u16*>(r3 + 8 + 2 * l));
        const u16* p0 = xpb + (size_t)ns0.y * DIM + l * 16;
        const u16* p1 = xpb + (size_t)ns1.y * DIM + l * 16;
        const u16* p2 = xpb + (size_t)ns2.y * DIM + l * 16;
        const u16* p3 = xpb + (size_t)ns3.y * DIM + l * 16;
        short8 ua0 = *reinterpret_cast<const short8*>(p0);
        short8 ub0 = *reinterpret_cast<const short8*>(p0 + 8);
        short8 ua1 = *reinterpret_cast<const short8*>(p1);
        short8 ub1 = *reinterpret_cast<const short8*>(p1 + 8);
        short8 ua2 = *reinterpret_cast<const short8*>(p2);
        short8 ub2 = *reinterpret_cast<const short8*>(p2 + 8);
        short8 ua3 = *reinterpret_cast<const short8*>(p3);
        short8 ub3 = *reinterpret_cast<const short8*>(p3 + 8);
        float m0 = e0 >= 0 ? g0 : 0.0f;
        float m1 = e1 >= 0 ? g1 : 0.0f;
        float m2 = e2 >= 0 ? g2 : 0.0f;
        float m3 = e3 >= 0 ? g3 : 0.0f;
        #pragma unroll
        for (int i = 0; i < 8; ++i) {
            acc[i]     += m0 * bf2f((u16)ua0[i]) + m1 * bf2f((u16)ua1[i])
                        + m2 * bf2f((u16)ua2[i]) + m3 * bf2f((u16)ua3[i]);
            acc[8 + i] += m0 * bf2f((u16)ub0[i]) + m1 * bf2f((u16)ub1[i])
                        + m2 * bf2f((u16)ub2[i]) + m3 * bf2f((u16)ub3[i]);
        }
        e0 = e0 >= 0 ? ns0.x : -1;
        e1 = e1 >= 0 ? ns1.x : -1;
        e2 = e2 >= 0 ? ns2.x : -1;
        e3 = e3 >= 0 ? ns3.x : -1;
    }

    // 64B per lane, 512B per node, contiguous; non-temporal (write-once)
    f32x4* op = reinterpret_cast<f32x4*>(out + (size_t)n * DIM + l * 16);
    #pragma unroll
    for (int q = 0; q < 4; ++q) {
        f32x4 o = {acc[q * 4 + 0], acc[q * 4 + 1], acc[q * 4 + 2], acc[q * 4 + 3]};
        __builtin_nontemporal_store(o, op + q);
    }
}

// ---------------------------------------------------------------------------
// Fallback (small ws): per-edge atomic scatter reading bf16 xp
// ---------------------------------------------------------------------------
__global__ __launch_bounds__(256) void edge_scatter(const int* __restrict__ ei,
                                                    const float* __restrict__ ea,
                                                    const float* __restrict__ We,
                                                    const float* __restrict__ be,
                                                    const u16* __restrict__ xpb,
                                                    float* __restrict__ out) {
    __shared__ float sW[HEADS * EDIM];
    __shared__ float sb[HEADS];
    if (threadIdx.x < HEADS * EDIM) sW[threadIdx.x] = We[threadIdx.x];
    if (threadIdx.x < HEADS) sb[threadIdx.x] = be[threadIdx.x];
    __syncthreads();

    const int t = blockIdx.x * 256 + threadIdx.x;
    const int e = t >> 5;
    const int l = t & 31;
    if (e >= EDGES) return;

    const int src = ei[e];
    const int tgt = ei[EDGES + e];
    const int h = l >> 2;

    float4 ea0 = *reinterpret_cast<const float4*>(ea + (size_t)e * EDIM);
    float4 ea1 = *reinterpret_cast<const float4*>(ea + (size_t)e * EDIM + 4);
    float4 wa = *reinterpret_cast<const float4*>(&sW[h * EDIM]);
    float4 wb = *reinterpret_cast<const float4*>(&sW[h * EDIM + 4]);
    float z = sb[h]
            + ea0.x * wa.x + ea0.y * wa.y + ea0.z * wa.z + ea0.w * wa.w
            + ea1.x * wb.x + ea1.y * wb.y + ea1.z * wb.z + ea1.w * wb.w;
    float g = 1.0f / (1.0f + __expf(-z));

    ushort4 u = *reinterpret_cast<const ushort4*>(xpb + (size_t)src * DIM + l * 4);
    float* op = out + (size_t)tgt * DIM + l * 4;
    unsafeAtomicAdd(op + 0, bf2f(u.x) * g);
    unsafeAtomicAdd(op + 1, bf2f(u.y) * g);
    unsafeAtomicAdd(op + 2, bf2f(u.z) * g);
    unsafeAtomicAdd(op + 3, bf2f(u.w) * g);
}

// ---------------------------------------------------------------------------
extern "C" void kernel_launch(void* const* d_in, const int* in_sizes, int n_in,
                              void* d_out, int out_size, void* d_ws, size_t ws_size,
                              hipStream_t stream) {
    const float* x   = (const float*)d_in[0];
    const int*   ei  = (const int*)d_in[1];
    const float* eat = (const float*)d_in[2];
    const float* Wn  = (const float*)d_in[3];
    const float* bn  = (const float*)d_in[4];
    const float* We  = (const float*)d_in[5];
    const float* be  = (const float*)d_in[6];
    float* out = (float*)d_out;

    // workspace layout (all segments 16B-aligned)
    u16* xpb   = (u16*)d_ws;                                // NODES*128 bf16 (25.6MB)
    int* head4 = (int*)(xpb + (size_t)NODES * DIM);         // NODES*4 i32 (1.6MB)
    char* rec  = (char*)(head4 + (size_t)NODES * 4);        // EDGES*32 B (25.6MB)

    const size_t need = (size_t)NODES * DIM * 2 + (size_t)NODES * 16
                      + (size_t)EDGES * 32;                 // ~52.8 MB
    const size_t need_fb = (size_t)NODES * DIM * 2;         // fallback: xpb only

    if (ws_size >= need) {
        hipMemsetAsync(head4, 0xFF, (size_t)NODES * 16, stream);  // head4 = -1
        build_rec<<<(EDGES + 255) / 256, 256, 0, stream>>>(ei, eat, We, be,
                                                           head4, (uint4*)rec);
        node_proj_mfma<<<(NODES + 127) / 128, 256, 0, stream>>>(x, Wn, bn, xpb);
        aggregate_v8<<<(NODES + 31) / 32, 256, 0, stream>>>(xpb, head4, rec, out);
    } else if (ws_size >= need_fb) {
        node_proj_mfma<<<(NODES + 127) / 128, 256, 0, stream>>>(x, Wn, bn, xpb);
        hipMemsetAsync(d_out, 0, (size_t)out_size * sizeof(float), stream);
        edge_scatter<<<(EDGES * 32) / 256, 256, 0, stream>>>(ei, eat, We, be, xpb, out);
    }
}

// Round 11
// 110.416 us; speedup vs baseline: 1.1784x; 1.1784x over previous
//
#include <hip/hip_runtime.h>

typedef unsigned char u8;
typedef unsigned short u16;
typedef unsigned int u32;
typedef __attribute__((ext_vector_type(8))) short short8;   // bf16x8 MFMA frag
typedef __attribute__((ext_vector_type(4))) float f32x4;    // MFMA acc frag

// Problem constants (match reference)
constexpr int NODES = 100000;
constexpr int EDGES = 800000;
constexpr int DIM = 128;       // node dim
constexpr int EDIM = 8;        // edge attr dim
constexpr int HEADS = 8;

__device__ inline u16 f2bf(float f) {              // f32 -> bf16 RNE
    u32 u = __float_as_uint(f);
    u = (u + 0x7FFFu + ((u >> 16) & 1u)) >> 16;
    return (u16)u;
}
__device__ inline float bf2f(u16 s) {              // bf16 -> f32 exact
    return __uint_as_float(((u32)s) << 16);
}

// ---------------------------------------------------------------------------
// node_proj via MFMA (R4-proven structure, inline W f32->bf16 staging).
// Also initializes head4[] to -1 (runs before build_rec; stream ordering
// makes the init visible to build_rec's atomics — saves a memset dispatch).
// ---------------------------------------------------------------------------
__global__ __launch_bounds__(256) void node_proj_mfma(const float* __restrict__ x,
                                                      const float* __restrict__ Wn,
                                                      const float* __restrict__ bn,
                                                      u16* __restrict__ xpb,
                                                      int* __restrict__ head4) {
    __shared__ u16 sW[128 * 136];   // 34816 B, +8 pad per row

    const int tid = threadIdx.x;

    {   // init head4: 400000 ints, 2 per thread across the grid
        int t = blockIdx.x * 256 + tid;
        if (t < NODES * 2) {
            head4[2 * t] = -1;
            head4[2 * t + 1] = -1;
        }
    }

    {   // stage W: f32 global -> bf16 LDS, 128 rows x 16 chunks of 8
        #pragma unroll
        for (int i = tid; i < 128 * 16; i += 256) {
            int row = i >> 4, ch = i & 15;
            const float* p = Wn + row * DIM + ch * 8;
            float4 f0 = *reinterpret_cast<const float4*>(p);
            float4 f1 = *reinterpret_cast<const float4*>(p + 4);
            short8 v;
            v[0]=(short)f2bf(f0.x); v[1]=(short)f2bf(f0.y);
            v[2]=(short)f2bf(f0.z); v[3]=(short)f2bf(f0.w);
            v[4]=(short)f2bf(f1.x); v[5]=(short)f2bf(f1.y);
            v[6]=(short)f2bf(f1.z); v[7]=(short)f2bf(f1.w);
            *reinterpret_cast<short8*>(&sW[row * 136 + ch * 8]) = v;
        }
    }
    __syncthreads();

    const int w = tid >> 6;        // wave 0..3
    const int l = tid & 63;
    const int lr = l & 15;
    const int lh = l >> 4;
    const int m0 = blockIdx.x * 128 + w * 32;

    f32x4 acc[2][8];
    #pragma unroll
    for (int mt = 0; mt < 2; ++mt)
        #pragma unroll
        for (int nt = 0; nt < 8; ++nt) acc[mt][nt] = f32x4{0, 0, 0, 0};

    #pragma unroll
    for (int kk = 0; kk < 4; ++kk) {
        const int kb = kk * 32 + lh * 8;
        short8 a0, a1;
        {
            int row = m0 + lr;  row = row < NODES ? row : 0;
            const float* p = x + (size_t)row * DIM + kb;
            float4 f0 = *reinterpret_cast<const float4*>(p);
            float4 f1 = *reinterpret_cast<const float4*>(p + 4);
            a0[0]=(short)f2bf(f0.x); a0[1]=(short)f2bf(f0.y);
            a0[2]=(short)f2bf(f0.z); a0[3]=(short)f2bf(f0.w);
            a0[4]=(short)f2bf(f1.x); a0[5]=(short)f2bf(f1.y);
            a0[6]=(short)f2bf(f1.z); a0[7]=(short)f2bf(f1.w);
        }
        {
            int row = m0 + 16 + lr;  row = row < NODES ? row : 0;
            const float* p = x + (size_t)row * DIM + kb;
            float4 f0 = *reinterpret_cast<const float4*>(p);
            float4 f1 = *reinterpret_cast<const float4*>(p + 4);
            a1[0]=(short)f2bf(f0.x); a1[1]=(short)f2bf(f0.y);
            a1[2]=(short)f2bf(f0.z); a1[3]=(short)f2bf(f0.w);
            a1[4]=(short)f2bf(f1.x); a1[5]=(short)f2bf(f1.y);
            a1[6]=(short)f2bf(f1.z); a1[7]=(short)f2bf(f1.w);
        }
        #pragma unroll
        for (int nt = 0; nt < 8; ++nt) {
            short8 b = *reinterpret_cast<const short8*>(&sW[(nt * 16 + lr) * 136 + kb]);
            acc[0][nt] = __builtin_amdgcn_mfma_f32_16x16x32_bf16(a0, b, acc[0][nt], 0, 0, 0);
            acc[1][nt] = __builtin_amdgcn_mfma_f32_16x16x32_bf16(a1, b, acc[1][nt], 0, 0, 0);
        }
    }

    float bias[8];
    #pragma unroll
    for (int nt = 0; nt < 8; ++nt) bias[nt] = bn[nt * 16 + lr];

    #pragma unroll
    for (int mt = 0; mt < 2; ++mt) {
        #pragma unroll
        for (int r = 0; r < 4; ++r) {
            int grow = m0 + mt * 16 + lh * 4 + r;
            if (grow < NODES) {
                #pragma unroll
                for (int nt = 0; nt < 8; ++nt)
                    xpb[(size_t)grow * DIM + nt * 16 + lr] =
                        f2bf(acc[mt][nt][r] + bias[nt]);
            }
        }
    }
}

// ---------------------------------------------------------------------------
// build_rec: link-build + gate precompute. 16B record, coalesced at index e:
//   [0,4): next   [4,8): src   [8,16): 8 gates u8 (g = q/255, err <= 0.002)
// 4-way split lists: head4[tgt*4 + (e&3)]. Only head4 takes random atomics.
// ---------------------------------------------------------------------------
__global__ __launch_bounds__(256) void build_rec(const int* __restrict__ ei,
                                                 const float* __restrict__ ea,
                                                 const float* __restrict__ We,
                                                 const float* __restrict__ be,
                                                 int* __restrict__ head4,
                                                 uint4* __restrict__ rec) {
    __shared__ float sW[HEADS * EDIM];
    __shared__ float sb[HEADS];
    if (threadIdx.x < HEADS * EDIM) sW[threadIdx.x] = We[threadIdx.x];
    if (threadIdx.x < HEADS) sb[threadIdx.x] = be[threadIdx.x];
    __syncthreads();

    const int e = blockIdx.x * 256 + threadIdx.x;
    if (e >= EDGES) return;

    const int src = ei[e];
    const int tgt = ei[EDGES + e];
    float4 a0 = *reinterpret_cast<const float4*>(ea + (size_t)e * EDIM);
    float4 a1 = *reinterpret_cast<const float4*>(ea + (size_t)e * EDIM + 4);

    u32 q[HEADS];
    #pragma unroll
    for (int h = 0; h < HEADS; ++h) {
        const float* w = &sW[h * EDIM];
        float z = sb[h]
                + a0.x * w[0] + a0.y * w[1] + a0.z * w[2] + a0.w * w[3]
                + a1.x * w[4] + a1.y * w[5] + a1.z * w[6] + a1.w * w[7];
        float g = 1.0f / (1.0f + __expf(-z));
        q[h] = (u32)(g * 255.0f + 0.5f);
    }

    int nx = atomicExch(&head4[tgt * 4 + (e & 3)], e);

    uint4 r;
    r.x = (u32)nx;
    r.y = (u32)src;
    r.z = q[0] | (q[1] << 8) | (q[2] << 16) | (q[3] << 24);
    r.w = q[4] | (q[5] << 8) | (q[6] << 16) | (q[7] << 24);
    rec[e] = r;                       // coalesced 16B
}

// ---------------------------------------------------------------------------
// aggregate_v9: 16-lane group per node (proven v7 shape), 4 chains walked
// concurrently (branchless clamp + masked accumulate). 16B records: per hop
// ONE metadata line (4 records/line) + the 256B xpb row. Regular stores.
// ---------------------------------------------------------------------------
__global__ __launch_bounds__(256) void aggregate_v9(const u16* __restrict__ xpb,
                                                    const int* __restrict__ head4,
                                                    const char* __restrict__ recB,
                                                    float* __restrict__ out) {
    const int n = blockIdx.x * 16 + (threadIdx.x >> 4);
    if (n >= NODES) return;
    const int l = threadIdx.x & 15;    // lane in group
    const int h = l >> 1;              // head for this lane's 8 cols

    constexpr float DQ = 1.0f / 255.0f;

    float acc[8];
    #pragma unroll
    for (int i = 0; i < 8; ++i) acc[i] = 0.0f;

    int e0 = head4[n * 4 + 0];
    int e1 = head4[n * 4 + 1];
    int e2 = head4[n * 4 + 2];
    int e3 = head4[n * 4 + 3];

    while (e0 >= 0 || e1 >= 0 || e2 >= 0 || e3 >= 0) {
        int c0 = e0 >= 0 ? e0 : 0;
        int c1 = e1 >= 0 ? e1 : 0;
        int c2 = e2 >= 0 ? e2 : 0;
        int c3 = e3 >= 0 ? e3 : 0;
        const char* r0 = recB + (size_t)c0 * 16;
        const char* r1 = recB + (size_t)c1 * 16;
        const char* r2 = recB + (size_t)c2 * 16;
        const char* r3 = recB + (size_t)c3 * 16;
        int2 ns0 = *reinterpret_cast<const int2*>(r0);
        int2 ns1 = *reinterpret_cast<const int2*>(r1);
        int2 ns2 = *reinterpret_cast<const int2*>(r2);
        int2 ns3 = *reinterpret_cast<const int2*>(r3);
        float g0 = (float)*reinterpret_cast<const u8*>(r0 + 8 + h) * DQ;
        float g1 = (float)*reinterpret_cast<const u8*>(r1 + 8 + h) * DQ;
        float g2 = (float)*reinterpret_cast<const u8*>(r2 + 8 + h) * DQ;
        float g3 = (float)*reinterpret_cast<const u8*>(r3 + 8 + h) * DQ;
        short8 u0 = *reinterpret_cast<const short8*>(xpb + (size_t)ns0.y * DIM + l * 8);
        short8 u1 = *reinterpret_cast<const short8*>(xpb + (size_t)ns1.y * DIM + l * 8);
        short8 u2 = *reinterpret_cast<const short8*>(xpb + (size_t)ns2.y * DIM + l * 8);
        short8 u3 = *reinterpret_cast<const short8*>(xpb + (size_t)ns3.y * DIM + l * 8);
        float m0 = e0 >= 0 ? g0 : 0.0f;
        float m1 = e1 >= 0 ? g1 : 0.0f;
        float m2 = e2 >= 0 ? g2 : 0.0f;
        float m3 = e3 >= 0 ? g3 : 0.0f;
        #pragma unroll
        for (int i = 0; i < 8; ++i) {
            acc[i] += m0 * bf2f((u16)u0[i]);
            acc[i] += m1 * bf2f((u16)u1[i]);
            acc[i] += m2 * bf2f((u16)u2[i]);
            acc[i] += m3 * bf2f((u16)u3[i]);
        }
        e0 = e0 >= 0 ? ns0.x : -1;
        e1 = e1 >= 0 ? ns1.x : -1;
        e2 = e2 >= 0 ? ns2.x : -1;
        e3 = e3 >= 0 ? ns3.x : -1;
    }

    float4 o0 = {acc[0], acc[1], acc[2], acc[3]};
    float4 o1 = {acc[4], acc[5], acc[6], acc[7]};
    float4* op = reinterpret_cast<float4*>(out + (size_t)n * DIM + l * 8);
    op[0] = o0;
    op[1] = o1;
}

// ---------------------------------------------------------------------------
// Fallback (small ws): per-edge atomic scatter reading bf16 xp
// ---------------------------------------------------------------------------
__global__ __launch_bounds__(256) void edge_scatter(const int* __restrict__ ei,
                                                    const float* __restrict__ ea,
                                                    const float* __restrict__ We,
                                                    const float* __restrict__ be,
                                                    const u16* __restrict__ xpb,
                                                    float* __restrict__ out) {
    __shared__ float sW[HEADS * EDIM];
    __shared__ float sb[HEADS];
    if (threadIdx.x < HEADS * EDIM) sW[threadIdx.x] = We[threadIdx.x];
    if (threadIdx.x < HEADS) sb[threadIdx.x] = be[threadIdx.x];
    __syncthreads();

    const int t = blockIdx.x * 256 + threadIdx.x;
    const int e = t >> 5;
    const int l = t & 31;
    if (e >= EDGES) return;

    const int src = ei[e];
    const int tgt = ei[EDGES + e];
    const int h = l >> 2;

    float4 ea0 = *reinterpret_cast<const float4*>(ea + (size_t)e * EDIM);
    float4 ea1 = *reinterpret_cast<const float4*>(ea + (size_t)e * EDIM + 4);
    float4 wa = *reinterpret_cast<const float4*>(&sW[h * EDIM]);
    float4 wb = *reinterpret_cast<const float4*>(&sW[h * EDIM + 4]);
    float z = sb[h]
            + ea0.x * wa.x + ea0.y * wa.y + ea0.z * wa.z + ea0.w * wa.w
            + ea1.x * wb.x + ea1.y * wb.y + ea1.z * wb.z + ea1.w * wb.w;
    float g = 1.0f / (1.0f + __expf(-z));

    ushort4 u = *reinterpret_cast<const ushort4*>(xpb + (size_t)src * DIM + l * 4);
    float* op = out + (size_t)tgt * DIM + l * 4;
    unsafeAtomicAdd(op + 0, bf2f(u.x) * g);
    unsafeAtomicAdd(op + 1, bf2f(u.y) * g);
    unsafeAtomicAdd(op + 2, bf2f(u.z) * g);
    unsafeAtomicAdd(op + 3, bf2f(u.w) * g);
}

// ---------------------------------------------------------------------------
extern "C" void kernel_launch(void* const* d_in, const int* in_sizes, int n_in,
                              void* d_out, int out_size, void* d_ws, size_t ws_size,
                              hipStream_t stream) {
    const float* x   = (const float*)d_in[0];
    const int*   ei  = (const int*)d_in[1];
    const float* eat = (const float*)d_in[2];
    const float* Wn  = (const float*)d_in[3];
    const float* bn  = (const float*)d_in[4];
    const float* We  = (const float*)d_in[5];
    const float* be  = (const float*)d_in[6];
    float* out = (float*)d_out;

    // workspace layout (all segments 16B-aligned)
    u16* xpb   = (u16*)d_ws;                                // NODES*128 bf16 (25.6MB)
    int* head4 = (int*)(xpb + (size_t)NODES * DIM);         // NODES*4 i32 (1.6MB)
    char* rec  = (char*)(head4 + (size_t)NODES * 4);        // EDGES*16 B (12.8MB)

    const size_t need = (size_t)NODES * DIM * 2 + (size_t)NODES * 16
                      + (size_t)EDGES * 16;                 // ~40 MB
    const size_t need_fb = (size_t)NODES * DIM * 2;         // fallback: xpb only

    if (ws_size >= need) {
        node_proj_mfma<<<(NODES + 127) / 128, 256, 0, stream>>>(x, Wn, bn, xpb, head4);
        build_rec<<<(EDGES + 255) / 256, 256, 0, stream>>>(ei, eat, We, be,
                                                           head4, (uint4*)rec);
        aggregate_v9<<<(NODES + 15) / 16, 256, 0, stream>>>(xpb, head4, rec, out);
    } else if (ws_size >= need_fb) {
        node_proj_mfma<<<(NODES + 127) / 128, 256, 0, stream>>>(x, Wn, bn, xpb, head4);
        hipMemsetAsync(d_out, 0, (size_t)out_size * sizeof(float), stream);
        edge_scatter<<<(EDGES * 32) / 256, 256, 0, stream>>>(ei, eat, We, be, xpb, out);
    }
}